// Round 16
// baseline (188.636 us; speedup 1.0000x reference)
//
#include <hip/hip_runtime.h>
#include <hip/hip_bf16.h>
#include <math.h>

#define POST 128
#define NI 129            // T+1
#define NJK 4225          // 65*65
#define NTOT 16512        // 129*128
#define KBLKS 134         // af k-blocks of 32
#define MBLKS 32          // 512/16
#define ZSTRIDE 8454144   // 512*16512 floats per K-partial
#define PANEL_CLAMP 2163184u  // 4225*512 - 16 : last safe 16B source in a W1 panel

typedef __attribute__((ext_vector_type(8))) short bf16x8;
typedef __attribute__((ext_vector_type(4))) float f32x4;
typedef __attribute__((ext_vector_type(2))) unsigned int u32x2;

__device__ __forceinline__ unsigned short f2bf(float f){
    unsigned u = __builtin_bit_cast(unsigned, f);
    unsigned r = (u + 0x7FFFu + ((u >> 16) & 1u)) >> 16;   // RNE
    return (unsigned short)r;
}
__device__ __forceinline__ unsigned pack2(float a, float b){
    return (unsigned)f2bf(a) | ((unsigned)f2bf(b) << 16);
}
__device__ __forceinline__ unsigned cvtpk(float lo, float hi){
    unsigned r;
    asm("v_cvt_pk_bf16_f32 %0, %1, %2" : "=v"(r) : "v"(lo), "v"(hi));
    return r;
}

__device__ __forceinline__ void gload16(const void* g, void* l){
    __builtin_amdgcn_global_load_lds(
        (const __attribute__((address_space(1))) unsigned int*)g,
        (__attribute__((address_space(3))) unsigned int*)l, 16, 0, 0);
}

// ---------------- K1: build VA (bf16) in MFMA A-fragment granule order --------
__global__ void build_af(const float* __restrict__ audio,
                         const float* __restrict__ video,
                         uint4* __restrict__ af)
{
    int gid = blockIdx.x * 256 + threadIdx.x;
    if (gid >= KBLKS * MBLKS * 64) return;
    int lane = gid & 63;
    int mblk = (gid >> 6) & 31;
    int kblk = gid >> 11;
    int m  = mblk * 16 + (lane & 15);
    int k0 = kblk * 32 + (lane >> 4) * 8;
    float vals[8];
#pragma unroll
    for (int j = 0; j < 8; ++j){
        int k = k0 + j;
        float p = 0.f;
        if (k < NJK){
            int jj = k / 65;
            int kk = k - jj * 65;
            float a = (kk == 0) ? 1.f : audio[m * 64 + kk - 1];
            float v = (jj == 0) ? 1.f : video[m * 64 + jj - 1];
            p = a * v;
        }
        vals[j] = p;
    }
    uint4 o;
    o.x = pack2(vals[0], vals[1]);
    o.y = pack2(vals[2], vals[3]);
    o.z = pack2(vals[4], vals[5]);
    o.w = pack2(vals[6], vals[7]);
    af[gid] = o;
}

// ---------------- K2: fused Z = VA @ bf16(W1'), full-M blocks -----------------
// Block tile 512m x 64n, BK=32. Grid 1032 = 129 nt x 2 nh x 4 kq.
// 8 waves, each 64m x 64n (acc[4][4]). Each W1 element staged+converted by
// EXACTLY ONE block (no m-redundancy): B-HBM = 276 MB = floor.
// Per iter: A(4)->regs | STAGE(next, 1 gload16/wave) | vmcnt(5) | bar |
//   convert raw[p] fp32 -> frag bf16 [n][32k] swizzled (cvtpk) | lgkm0 bar |
//   16 MFMA/wave from A regs + frag b128.
// LDS 20KB: raw fp32 dbuf 2x8K | frag bf16 4K.  2 blocks/CU.
__global__ __launch_bounds__(512, 4) void fusion_gemm(
    const float* __restrict__ W1,
    const uint4* __restrict__ af,
    float* __restrict__ Zbase)
{
    __shared__ __align__(16) char lds[20480];

    // bijective XCD swizzle (nwg=1032 = 8*129)
    int orig = blockIdx.x;
    int xcd  = orig & 7;
    int w    = xcd * 129 + (orig >> 3);
    int nt  = w >> 3;         // 0..128
    int sub = w & 7;
    int nh  = sub & 1;        // n-half of the panel
    int kq  = sub >> 1;       // 0..3 k-quarter
    int k0 = (kq < 2) ? kq * 34 : 68 + (kq - 2) * 33;
    int NK = (kq < 2) ? 34 : 33;

    int t    = threadIdx.x;
    int lane = t & 63;
    int wv   = t >> 6;        // 0..7 : wave owns m-rows wv*64..+63

    f32x4 acc[4][4] = {};

    const char* wpanel = (const char*)(W1 + (size_t)nt * (NJK * 128));
    unsigned nhoff = (unsigned)nh * 256u;

    int n_c = t & 63;         // convert: this thread's n-column (0..63)

    uint4 vA[4];

    // stage: 1 gload16 per wave -> raw[pb] linear [32k][64n] fp32 (8KB)
#define STAGE(kb_, pb_)                                                         \
    do {                                                                        \
        unsigned bo_ = (unsigned)(kb_) * 16384u                                 \
                     + (unsigned)(wv * 4 + (lane >> 4)) * 512u                  \
                     + nhoff + (unsigned)(lane & 15) * 16u;                     \
        if (bo_ > PANEL_CLAMP) bo_ = PANEL_CLAMP;  /* tail-safe, A=0 there */   \
        gload16(wpanel + bo_, lds + (pb_) * 8192 + wv * 1024);                  \
    } while (0)

    // prologue
    STAGE(k0, 0);

    for (int it = 0; it < NK; ++it){
        int kblk = k0 + it;
        int p    = it & 1;

        // ---- A fragments (4 granules, unique per wave) -> regs
        const uint4* ab = af + ((size_t)kblk * 32 + wv * 4) * 64 + lane;
        vA[0] = ab[0];
        vA[1] = ab[64];
        vA[2] = ab[128];
        vA[3] = ab[192];
        __builtin_amdgcn_sched_barrier(0);

        // ---- stage next tile (stays in flight across this whole iteration)
        if (it + 1 < NK)
            STAGE(kblk + 1, p ^ 1);
        __builtin_amdgcn_sched_barrier(0);

        // ---- drain STAGE(kblk) only: 4 A + 1 next-stage remain in flight
        if (it + 1 < NK){
            asm volatile("s_waitcnt vmcnt(5)" ::: "memory");
        } else {
            asm volatile("s_waitcnt vmcnt(4)" ::: "memory");
        }
        __builtin_amdgcn_sched_barrier(0);
        __builtin_amdgcn_s_barrier();            // raw[p] visible; frag free

        // ---- CONVERT raw[p] fp32 [32k][64n] -> frag bf16 [n][32k] swizzled
        {
            const char* rawp = lds + p * 8192;
            char* fragp      = lds + 16384;
            float v0 = *(const float*)(rawp + (wv * 4 + 0) * 256 + n_c * 4);
            float v1 = *(const float*)(rawp + (wv * 4 + 1) * 256 + n_c * 4);
            float v2 = *(const float*)(rawp + (wv * 4 + 2) * 256 + n_c * 4);
            float v3 = *(const float*)(rawp + (wv * 4 + 3) * 256 + n_c * 4);
            u32x2 uu;
            uu.x = cvtpk(v0, v1);
            uu.y = cvtpk(v2, v3);
            int byte = (n_c * 64 + wv * 8) ^ (((n_c >> 1) & 3) << 4);
            *(u32x2*)(fragp + byte) = uu;
        }
        asm volatile("s_waitcnt lgkmcnt(0)" ::: "memory");
        __builtin_amdgcn_sched_barrier(0);
        __builtin_amdgcn_s_barrier();            // frag ready

        // ---- MFMA: 16 per wave (64m x 64n), A regs + frag b128
        {
            const char* fragp = lds + 16384;
            bf16x8 b[4];
#pragma unroll
            for (int g = 0; g < 4; ++g){
                int n = g * 16 + (lane & 15);
                int byte = (n * 64 + (lane >> 4) * 16) ^ (((n >> 1) & 3) << 4);
                b[g] = *(const bf16x8*)(fragp + byte);
            }
            bf16x8 a0 = __builtin_bit_cast(bf16x8, vA[0]);
            bf16x8 a1 = __builtin_bit_cast(bf16x8, vA[1]);
            bf16x8 a2 = __builtin_bit_cast(bf16x8, vA[2]);
            bf16x8 a3 = __builtin_bit_cast(bf16x8, vA[3]);
#pragma unroll
            for (int g = 0; g < 4; ++g){
                acc[0][g] = __builtin_amdgcn_mfma_f32_16x16x32_bf16(a0, b[g], acc[0][g], 0, 0, 0);
                acc[1][g] = __builtin_amdgcn_mfma_f32_16x16x32_bf16(a1, b[g], acc[1][g], 0, 0, 0);
                acc[2][g] = __builtin_amdgcn_mfma_f32_16x16x32_bf16(a2, b[g], acc[2][g], 0, 0, 0);
                acc[3][g] = __builtin_amdgcn_mfma_f32_16x16x32_bf16(a3, b[g], acc[3][g], 0, 0, 0);
            }
        }
    }

    // epilogue: D layout col=lane&15, row=(lane>>4)*4+reg
    float* Zp = Zbase + (size_t)kq * ZSTRIDE;
    int row0 = wv * 64 + (lane >> 4) * 4;
    int col0 = nt * 128 + nh * 64 + (lane & 15);
#pragma unroll
    for (int f = 0; f < 4; ++f)
#pragma unroll
        for (int g = 0; g < 4; ++g)
#pragma unroll
            for (int r = 0; r < 4; ++r)
                Zp[(size_t)(row0 + f * 16 + r) * NTOT + col0 + g * 16] = acc[f][g][r];
}

// ---------------- K3: y1 = relu(b1 + sum_i t1_i * sum_q Zq); y2; sigmoid ------
__global__ void tail_mlp(const float* __restrict__ Zbase,
                         const float* __restrict__ text,
                         const float* __restrict__ b1,
                         const float* __restrict__ W2,
                         const float* __restrict__ b2,
                         const float* __restrict__ W3,
                         const float* __restrict__ b3,
                         float* __restrict__ out)
{
    int b   = blockIdx.x;     // 512
    int tid = threadIdx.x;    // 128
    __shared__ float t1s[NI];
    __shared__ float y1s[POST];
    __shared__ float red[2];

    t1s[tid + 1] = text[b * 128 + tid];
    if (tid == 0) t1s[0] = 1.f;
    __syncthreads();

    const float* z0 = Zbase + (size_t)b * NTOT;
    const float* z1 = z0 + (size_t)ZSTRIDE;
    const float* z2 = z0 + (size_t)2 * ZSTRIDE;
    const float* z3 = z0 + (size_t)3 * ZSTRIDE;
    float acc = 0.f;
    for (int i = 0; i < NI; ++i){
        int idx = i * 128 + tid;
        float zv = z0[idx] + z1[idx] + z2[idx] + z3[idx];
        acc = fmaf(t1s[i], zv, acc);
    }
    acc += b1[tid];
    float y1 = fmaxf(acc, 0.f);
    y1s[tid] = y1;
    __syncthreads();

    float a2 = b2[tid];
    for (int q = 0; q < 128; ++q)
        a2 = fmaf(y1s[q], W2[q * 128 + tid], a2);
    float y2 = fmaxf(a2, 0.f);

    float part = y2 * W3[tid];
#pragma unroll
    for (int off = 32; off > 0; off >>= 1)
        part += __shfl_down(part, off);
    if ((tid & 63) == 0) red[tid >> 6] = part;
    __syncthreads();
    if (tid == 0){
        float z = red[0] + red[1] + b3[0];
        out[b] = 6.f / (1.f + expf(-z)) - 3.f;
    }
}

extern "C" void kernel_launch(void* const* d_in, const int* in_sizes, int n_in,
                              void* d_out, int out_size, void* d_ws, size_t ws_size,
                              hipStream_t stream)
{
    const float* audio = (const float*)d_in[0];
    const float* video = (const float*)d_in[1];
    const float* text  = (const float*)d_in[2];
    const float* W1    = (const float*)d_in[3];
    const float* b1    = (const float*)d_in[4];
    const float* W2    = (const float*)d_in[5];
    const float* b2    = (const float*)d_in[6];
    const float* W3    = (const float*)d_in[7];
    const float* b3    = (const float*)d_in[8];
    float* out = (float*)d_out;

    char* ws = (char*)d_ws;
    uint4* af    = (uint4*)ws;                    // 4,390,912 B
    float* Zbase = (float*)(ws + (8u << 20));     // 4 x 33,816,576 B partials

    int af_granules = KBLKS * MBLKS * 64;         // 274432 threads
    build_af<<<(af_granules + 255) / 256, 256, 0, stream>>>(audio, video, af);
    fusion_gemm<<<1032, 512, 0, stream>>>(W1, af, Zbase);
    tail_mlp<<<512, 128, 0, stream>>>(Zbase, text, b1, W2, b2, W3, b3, out);
}

// Round 18
// 188.174 us; speedup vs baseline: 1.0025x; 1.0025x over previous
//
#include <hip/hip_runtime.h>
#include <hip/hip_bf16.h>
#include <math.h>

#define POST 128
#define NI 129            // T+1
#define NJK 4225          // 65*65
#define NTOT 16512        // 129*128
#define KBLKS 134         // af k-blocks of 32
#define MBLKS 32          // 512/16
#define KSTEPS32 133      // k-steps of 32 (covers k<4256; A=0 past 4224)
#define PANEL_CLAMP 2163184u  // 4225*512 - 16 : last safe 16B source in a W1 panel

typedef __attribute__((ext_vector_type(8))) short bf16x8;
typedef __attribute__((ext_vector_type(4))) float f32x4;
typedef __attribute__((ext_vector_type(4))) unsigned int u32x4;

__device__ __forceinline__ unsigned short f2bf(float f){
    unsigned u = __builtin_bit_cast(unsigned, f);
    unsigned r = (u + 0x7FFFu + ((u >> 16) & 1u)) >> 16;   // RNE
    return (unsigned short)r;
}
__device__ __forceinline__ unsigned pack2(float a, float b){
    return (unsigned)f2bf(a) | ((unsigned)f2bf(b) << 16);
}
__device__ __forceinline__ unsigned cvtpk(float lo, float hi){
    unsigned r;
    asm("v_cvt_pk_bf16_f32 %0, %1, %2" : "=v"(r) : "v"(lo), "v"(hi));
    return r;
}

__device__ __forceinline__ void gload16(const void* g, void* l){
    __builtin_amdgcn_global_load_lds(
        (const __attribute__((address_space(1))) unsigned int*)g,
        (__attribute__((address_space(3))) unsigned int*)l, 16, 0, 0);
}

// ---------------- K1: build VA (bf16) in MFMA A-fragment granule order --------
__global__ void build_af(const float* __restrict__ audio,
                         const float* __restrict__ video,
                         uint4* __restrict__ af)
{
    int gid = blockIdx.x * 256 + threadIdx.x;
    if (gid >= KBLKS * MBLKS * 64) return;
    int lane = gid & 63;
    int mblk = (gid >> 6) & 31;
    int kblk = gid >> 11;
    int m  = mblk * 16 + (lane & 15);
    int k0 = kblk * 32 + (lane >> 4) * 8;
    float vals[8];
#pragma unroll
    for (int j = 0; j < 8; ++j){
        int k = k0 + j;
        float p = 0.f;
        if (k < NJK){
            int jj = k / 65;
            int kk = k - jj * 65;
            float a = (kk == 0) ? 1.f : audio[m * 64 + kk - 1];
            float v = (jj == 0) ? 1.f : video[m * 64 + jj - 1];
            p = a * v;
        }
        vals[j] = p;
    }
    uint4 o;
    o.x = pack2(vals[0], vals[1]);
    o.y = pack2(vals[2], vals[3]);
    o.z = pack2(vals[4], vals[5]);
    o.w = pack2(vals[6], vals[7]);
    af[gid] = o;
}

// ---------------- K2: fused Z = VA @ bf16(W1')  -------------------------------
// R12 (156us) structure + A-direct-to-regs + split-K x2.
// 128x128 tile, BK=32, grid 1032 = 4 mt x 129 nt x 2 kb, 4 waves (2x2 of 64x64).
// B: raw fp32 via gload_lds, SOURCE-swizzled granules (2-way conflict-free
// gather); convert at fragment-read via cvtpk. A: af granules -> regs (L2).
// Loop: A->regs | STAGE(ks+1) | vmcnt(8) | bar | gather+cvt+MFMA | bar.
// LDS 32KB (B dbuf only) -> 4+ blocks/CU.
__global__ __launch_bounds__(256, 4) void fusion_gemm(
    const float* __restrict__ W1,
    const uint4* __restrict__ af,
    float* __restrict__ Z0,
    float* __restrict__ Z1)
{
    __shared__ __align__(16) char lds[32768];   // B raw fp32 dbuf (2x16K)

    // bijective XCD swizzle (nwg=1032 = 8*129): 8 sub-blocks of one nt per XCD
    int orig = blockIdx.x;
    int xcd  = orig & 7;
    int w    = xcd * 129 + (orig >> 3);
    int nt  = w >> 3;         // 0..128
    int sub = w & 7;
    int mt  = sub & 3;        // 0..3
    int kb  = sub >> 2;       // 0..1

    int ks0 = kb ? 67 : 0;
    int ks1 = kb ? KSTEPS32 : 67;

    int t    = threadIdx.x;
    int lane = t & 63;
    int wv   = t >> 6;
    int wm   = wv >> 1, wn = wv & 1;

    f32x4 acc[4][4] = {};

    const char* wpanel = (const char*)(W1 + (size_t)nt * (NJK * 128));

    // B staging source swizzle (involution): k = 2*cb + (lane>>5),
    // ng_src = (lane&31) ^ (((k>>3)&1)<<2); LDS dest stays linear.
#define STAGE(ks_, pb_)                                                         \
    do {                                                                        \
        char* dstB_ = lds + (pb_) * 16384;                                      \
        _Pragma("unroll")                                                       \
        for (int i_ = 0; i_ < 4; ++i_){                                         \
            int cb_ = wv * 4 + i_;                                              \
            int k_  = 2 * cb_ + (lane >> 5);                                    \
            int ngs_ = (lane & 31) ^ (((k_ >> 3) & 1) << 2);                    \
            unsigned bo_ = (unsigned)(ks_) * 16384u                             \
                         + (unsigned)k_ * 512u + (unsigned)ngs_ * 16u;          \
            if (bo_ > PANEL_CLAMP) bo_ = PANEL_CLAMP;  /* tail-safe */          \
            gload16(wpanel + bo_, dstB_ + cb_ * 1024);                          \
        }                                                                       \
    } while (0)

    // prologue: stage first tile
    STAGE(ks0, 0);

    for (int ks = ks0; ks < ks1; ++ks){
        int it = ks - ks0;
        int p  = it & 1;

        // ---- A fragments for tile ks -> regs (pinned at iter top)
        const uint4* ab = af + ((size_t)ks * 32 + mt * 8 + wm * 4) * 64 + lane;
        uint4 vA0 = ab[0];
        uint4 vA1 = ab[64];
        uint4 vA2 = ab[128];
        uint4 vA3 = ab[192];
        __builtin_amdgcn_sched_barrier(0);

        // ---- stage NEXT tile into buf p^1 (in flight across this iter)
        if (ks + 1 < ks1)
            STAGE(ks + 1, p ^ 1);
        __builtin_amdgcn_sched_barrier(0);

        // ---- drain B(ks) only: A(4) + nextB(4) may remain outstanding
        if (ks + 1 < ks1){
            asm volatile("s_waitcnt vmcnt(8)" ::: "memory");
        } else {
            asm volatile("s_waitcnt vmcnt(4)" ::: "memory");
        }
        __builtin_amdgcn_sched_barrier(0);
        __builtin_amdgcn_s_barrier();            // raw[p] visible to all waves

        // ---- gather + cvtpk + MFMA from raw[p]
        {
            const char* rawp = lds + p * 16384;
            int h  = lane >> 4;                  // k-group 0..3 (k = h*8+j)
            int fx = (h & 1) << 2;               // read-side swizzle

            bf16x8 b[4];
#pragma unroll
            for (int g = 0; g < 4; ++g){
                int n = wn * 64 + g * 16 + (lane & 15);
                const char* bp = rawp + (h * 8) * 512
                               + (((n >> 2) ^ fx) * 16) + (n & 3) * 4;
                float v[8];
#pragma unroll
                for (int j = 0; j < 8; ++j)
                    v[j] = *(const float*)(bp + j * 512);
                u32x4 ub;
                ub.x = cvtpk(v[0], v[1]);
                ub.y = cvtpk(v[2], v[3]);
                ub.z = cvtpk(v[4], v[5]);
                ub.w = cvtpk(v[6], v[7]);
                b[g] = __builtin_bit_cast(bf16x8, ub);
            }

            bf16x8 a0 = __builtin_bit_cast(bf16x8, vA0);
            bf16x8 a1 = __builtin_bit_cast(bf16x8, vA1);
            bf16x8 a2 = __builtin_bit_cast(bf16x8, vA2);
            bf16x8 a3 = __builtin_bit_cast(bf16x8, vA3);
#pragma unroll
            for (int g = 0; g < 4; ++g){
                acc[0][g] = __builtin_amdgcn_mfma_f32_16x16x32_bf16(a0, b[g], acc[0][g], 0, 0, 0);
                acc[1][g] = __builtin_amdgcn_mfma_f32_16x16x32_bf16(a1, b[g], acc[1][g], 0, 0, 0);
                acc[2][g] = __builtin_amdgcn_mfma_f32_16x16x32_bf16(a2, b[g], acc[2][g], 0, 0, 0);
                acc[3][g] = __builtin_amdgcn_mfma_f32_16x16x32_bf16(a3, b[g], acc[3][g], 0, 0, 0);
            }
        }

        __builtin_amdgcn_sched_barrier(0);
        __builtin_amdgcn_s_barrier();            // all waves done reading buf p
    }

    // epilogue: D layout col=lane&15, row=(lane>>4)*4+reg
    float* Zp = kb ? Z1 : Z0;
    int row0 = mt * 128 + wm * 64 + (lane >> 4) * 4;
    int col0 = nt * 128 + wn * 64 + (lane & 15);
#pragma unroll
    for (int f = 0; f < 4; ++f)
#pragma unroll
        for (int g = 0; g < 4; ++g)
#pragma unroll
            for (int r = 0; r < 4; ++r)
                Zp[(size_t)(row0 + f * 16 + r) * NTOT + col0 + g * 16] = acc[f][g][r];
}

// ---------------- K3: y1 = relu(b1 + sum_i t1_i * (Z0+Z1)); y2; sigmoid head ---
__global__ void tail_mlp(const float* __restrict__ Z0,
                         const float* __restrict__ Z1,
                         const float* __restrict__ text,
                         const float* __restrict__ b1,
                         const float* __restrict__ W2,
                         const float* __restrict__ b2,
                         const float* __restrict__ W3,
                         const float* __restrict__ b3,
                         float* __restrict__ out)
{
    int b   = blockIdx.x;     // 512
    int tid = threadIdx.x;    // 128
    __shared__ float t1s[NI];
    __shared__ float y1s[POST];
    __shared__ float red[2];

    t1s[tid + 1] = text[b * 128 + tid];
    if (tid == 0) t1s[0] = 1.f;
    __syncthreads();

    const float* z0 = Z0 + (size_t)b * NTOT;
    const float* z1 = Z1 + (size_t)b * NTOT;
    float acc = 0.f;
    for (int i = 0; i < NI; ++i)
        acc = fmaf(t1s[i], z0[i * 128 + tid] + z1[i * 128 + tid], acc);
    acc += b1[tid];
    float y1 = fmaxf(acc, 0.f);
    y1s[tid] = y1;
    __syncthreads();

    float a2 = b2[tid];
    for (int q = 0; q < 128; ++q)
        a2 = fmaf(y1s[q], W2[q * 128 + tid], a2);
    float y2 = fmaxf(a2, 0.f);

    float part = y2 * W3[tid];
#pragma unroll
    for (int off = 32; off > 0; off >>= 1)
        part += __shfl_down(part, off);
    if ((tid & 63) == 0) red[tid >> 6] = part;
    __syncthreads();
    if (tid == 0){
        float z = red[0] + red[1] + b3[0];
        out[b] = 6.f / (1.f + expf(-z)) - 3.f;
    }
}

extern "C" void kernel_launch(void* const* d_in, const int* in_sizes, int n_in,
                              void* d_out, int out_size, void* d_ws, size_t ws_size,
                              hipStream_t stream)
{
    const float* audio = (const float*)d_in[0];
    const float* video = (const float*)d_in[1];
    const float* text  = (const float*)d_in[2];
    const float* W1    = (const float*)d_in[3];
    const float* b1    = (const float*)d_in[4];
    const float* W2    = (const float*)d_in[5];
    const float* b2    = (const float*)d_in[6];
    const float* W3    = (const float*)d_in[7];
    const float* b3    = (const float*)d_in[8];
    float* out = (float*)d_out;

    char* ws = (char*)d_ws;
    uint4* af = (uint4*)ws;                       // 4,390,912 B
    float* Z0 = (float*)(ws + (8u  << 20));       // 33,816,576 B
    float* Z1 = (float*)(ws + (48u << 20));       // 33,816,576 B

    int af_granules = KBLKS * MBLKS * 64;         // 274432 threads
    build_af<<<(af_granules + 255) / 256, 256, 0, stream>>>(audio, video, af);
    fusion_gemm<<<1032, 256, 0, stream>>>(W1, af, Z0, Z1);
    tail_mlp<<<512, 128, 0, stream>>>(Z0, Z1, text, b1, W2, b2, W3, b3, out);
}

// Round 19
// 181.083 us; speedup vs baseline: 1.0417x; 1.0392x over previous
//
#include <hip/hip_runtime.h>
#include <hip/hip_bf16.h>
#include <math.h>

#define POST 128
#define NI 129            // T+1
#define NJK 4225          // 65*65
#define NTOT 16512        // 129*128
#define KBLKS 134         // af k-blocks of 32
#define MBLKS 32          // 512/16
#define KSTEPS32 133      // k-steps of 32 (covers k<4256; A=0 past 4224)
#define PANEL_CLAMP 2163184u  // 4225*512 - 16 : last safe 16B source in a W1 panel

typedef __attribute__((ext_vector_type(8))) short bf16x8;
typedef __attribute__((ext_vector_type(4))) float f32x4;
typedef __attribute__((ext_vector_type(4))) unsigned int u32x4;

__device__ __forceinline__ unsigned short f2bf(float f){
    unsigned u = __builtin_bit_cast(unsigned, f);
    unsigned r = (u + 0x7FFFu + ((u >> 16) & 1u)) >> 16;   // RNE
    return (unsigned short)r;
}
__device__ __forceinline__ unsigned pack2(float a, float b){
    return (unsigned)f2bf(a) | ((unsigned)f2bf(b) << 16);
}
__device__ __forceinline__ unsigned cvtpk(float lo, float hi){
    unsigned r;
    asm("v_cvt_pk_bf16_f32 %0, %1, %2" : "=v"(r) : "v"(lo), "v"(hi));
    return r;
}

__device__ __forceinline__ void gload16(const void* g, void* l){
    __builtin_amdgcn_global_load_lds(
        (const __attribute__((address_space(1))) unsigned int*)g,
        (__attribute__((address_space(3))) unsigned int*)l, 16, 0, 0);
}

// ---------------- K1: build VA (bf16) in MFMA A-fragment granule order --------
__global__ void build_af(const float* __restrict__ audio,
                         const float* __restrict__ video,
                         uint4* __restrict__ af)
{
    int gid = blockIdx.x * 256 + threadIdx.x;
    if (gid >= KBLKS * MBLKS * 64) return;
    int lane = gid & 63;
    int mblk = (gid >> 6) & 31;
    int kblk = gid >> 11;
    int m  = mblk * 16 + (lane & 15);
    int k0 = kblk * 32 + (lane >> 4) * 8;
    float vals[8];
#pragma unroll
    for (int j = 0; j < 8; ++j){
        int k = k0 + j;
        float p = 0.f;
        if (k < NJK){
            int jj = k / 65;
            int kk = k - jj * 65;
            float a = (kk == 0) ? 1.f : audio[m * 64 + kk - 1];
            float v = (jj == 0) ? 1.f : video[m * 64 + jj - 1];
            p = a * v;
        }
        vals[j] = p;
    }
    uint4 o;
    o.x = pack2(vals[0], vals[1]);
    o.y = pack2(vals[2], vals[3]);
    o.z = pack2(vals[4], vals[5]);
    o.w = pack2(vals[6], vals[7]);
    af[gid] = o;
}

// ---------------- K2: fused Z = VA @ bf16(W1')  -------------------------------
// 128x128 tile, BK=32, grid 516 = 4 mt x 129 nt, 4 waves (2x2 of 64x64).
// B: raw fp32, TRIPLE-buffered gload_lds, depth-2 prefetch, exact counted
//    vmcnt (16/12/4) -> steady-state wait is a no-op.
// A: af granules -> regs, prefetched ONE iter ahead (named cur/nxt sets).
// Gather+cvtpk+MFMA identical to the R12 156us kernel (verified).
__global__ __launch_bounds__(256, 3) void fusion_gemm(
    const float* __restrict__ W1,
    const uint4* __restrict__ af,
    float* __restrict__ Z)
{
    __shared__ __align__(16) char lds[49152];   // B raw fp32, 3 x 16K

    // bijective XCD swizzle (nwg=516: q=64, r=4)
    int orig = blockIdx.x;
    int xcd  = orig & 7;
    int base = (xcd < 4) ? xcd * 65 : 260 + (xcd - 4) * 64;
    int w    = base + (orig >> 3);
    int nt = w >> 2;          // 0..128
    int mt = w & 3;           // 0..3

    int t    = threadIdx.x;
    int lane = t & 63;
    int wv   = t >> 6;
    int wm   = wv >> 1, wn = wv & 1;

    f32x4 acc[4][4] = {};

    const char* wpanel = (const char*)(W1 + (size_t)nt * (NJK * 128));

    // B staging source swizzle (involution): k = 2*cb + (lane>>5),
    // ng_src = (lane&31) ^ (((k>>3)&1)<<2); LDS dest stays linear.
#define STAGE(ks_, pb_)                                                         \
    do {                                                                        \
        char* dstB_ = lds + (pb_) * 16384;                                      \
        _Pragma("unroll")                                                       \
        for (int i_ = 0; i_ < 4; ++i_){                                         \
            int cb_ = wv * 4 + i_;                                              \
            int k_  = 2 * cb_ + (lane >> 5);                                    \
            int ngs_ = (lane & 31) ^ (((k_ >> 3) & 1) << 2);                    \
            unsigned bo_ = (unsigned)(ks_) * 16384u                             \
                         + (unsigned)k_ * 512u + (unsigned)ngs_ * 16u;          \
            if (bo_ > PANEL_CLAMP) bo_ = PANEL_CLAMP;  /* tail-safe */          \
            gload16(wpanel + bo_, dstB_ + cb_ * 1024);                          \
        }                                                                       \
    } while (0)

#define ALOAD(ks_, d0, d1, d2, d3)                                             \
    do {                                                                        \
        const uint4* ab_ = af + ((size_t)(ks_) * 32 + mt * 8 + wm * 4) * 64 + lane; \
        d0 = ab_[0]; d1 = ab_[64]; d2 = ab_[128]; d3 = ab_[192];                \
    } while (0)

    uint4 aC0, aC1, aC2, aC3, aN0, aN1, aN2, aN3;

    // prologue: B tiles 0,1 in flight; A(0) in regs
    STAGE(0, 0);
    STAGE(1, 1);
    ALOAD(0, aC0, aC1, aC2, aC3);

    int p = 0, q = 2;     // q = (it+2)%3

    for (int ks = 0; ks < KSTEPS32; ++ks){
        // ---- A(ks+1) -> nxt regs (hidden across this iter)
        if (ks + 1 < KSTEPS32)
            ALOAD(ks + 1, aN0, aN1, aN2, aN3);
        __builtin_amdgcn_sched_barrier(0);

        // ---- STAGE(ks+2) -> buf q (in flight for 2 iterations)
        if (ks + 2 < KSTEPS32)
            STAGE(ks + 2, q);
        __builtin_amdgcn_sched_barrier(0);

        // ---- wait for B(ks): exact newer-load count (A ks; B ks+1; A ks+1; B ks+2)
        if (ks + 2 < KSTEPS32){
            asm volatile("s_waitcnt vmcnt(16)" ::: "memory");
        } else if (ks + 1 < KSTEPS32){
            asm volatile("s_waitcnt vmcnt(12)" ::: "memory");
        } else {
            asm volatile("s_waitcnt vmcnt(4)" ::: "memory");
        }
        __builtin_amdgcn_sched_barrier(0);
        __builtin_amdgcn_s_barrier();            // raw[p] visible to all waves

        // ---- gather + cvtpk + MFMA from raw[p]
        {
            const char* rawp = lds + p * 16384;
            int h  = lane >> 4;                  // k-group 0..3 (k = h*8+j)
            int fx = (h & 1) << 2;               // read-side swizzle

            bf16x8 b[4];
#pragma unroll
            for (int g = 0; g < 4; ++g){
                int n = wn * 64 + g * 16 + (lane & 15);
                const char* bp = rawp + (h * 8) * 512
                               + (((n >> 2) ^ fx) * 16) + (n & 3) * 4;
                float v[8];
#pragma unroll
                for (int j = 0; j < 8; ++j)
                    v[j] = *(const float*)(bp + j * 512);
                u32x4 ub;
                ub.x = cvtpk(v[0], v[1]);
                ub.y = cvtpk(v[2], v[3]);
                ub.z = cvtpk(v[4], v[5]);
                ub.w = cvtpk(v[6], v[7]);
                b[g] = __builtin_bit_cast(bf16x8, ub);
            }

            bf16x8 a0 = __builtin_bit_cast(bf16x8, aC0);
            bf16x8 a1 = __builtin_bit_cast(bf16x8, aC1);
            bf16x8 a2 = __builtin_bit_cast(bf16x8, aC2);
            bf16x8 a3 = __builtin_bit_cast(bf16x8, aC3);
#pragma unroll
            for (int g = 0; g < 4; ++g){
                acc[0][g] = __builtin_amdgcn_mfma_f32_16x16x32_bf16(a0, b[g], acc[0][g], 0, 0, 0);
                acc[1][g] = __builtin_amdgcn_mfma_f32_16x16x32_bf16(a1, b[g], acc[1][g], 0, 0, 0);
                acc[2][g] = __builtin_amdgcn_mfma_f32_16x16x32_bf16(a2, b[g], acc[2][g], 0, 0, 0);
                acc[3][g] = __builtin_amdgcn_mfma_f32_16x16x32_bf16(a3, b[g], acc[3][g], 0, 0, 0);
            }
        }

        __builtin_amdgcn_sched_barrier(0);
        __builtin_amdgcn_s_barrier();            // all waves done reading buf p

        // ---- rotate A regs and buffer indices
        aC0 = aN0; aC1 = aN1; aC2 = aN2; aC3 = aN3;
        p = (p == 2) ? 0 : p + 1;
        q = (q == 2) ? 0 : q + 1;
    }

    // epilogue: D layout col=lane&15, row=(lane>>4)*4+reg
    int row0 = mt * 128 + wm * 64 + (lane >> 4) * 4;
    int col0 = nt * 128 + wn * 64 + (lane & 15);
#pragma unroll
    for (int f = 0; f < 4; ++f)
#pragma unroll
        for (int g = 0; g < 4; ++g)
#pragma unroll
            for (int r = 0; r < 4; ++r)
                Z[(size_t)(row0 + f * 16 + r) * NTOT + col0 + g * 16] = acc[f][g][r];
}

// ---------------- K3: y1 = relu(b1 + sum_i t1_i * Z[:,i,:]); y2; sigmoid head --
__global__ void tail_mlp(const float* __restrict__ Z,
                         const float* __restrict__ text,
                         const float* __restrict__ b1,
                         const float* __restrict__ W2,
                         const float* __restrict__ b2,
                         const float* __restrict__ W3,
                         const float* __restrict__ b3,
                         float* __restrict__ out)
{
    int b   = blockIdx.x;     // 512
    int tid = threadIdx.x;    // 128
    __shared__ float t1s[NI];
    __shared__ float y1s[POST];
    __shared__ float red[2];

    t1s[tid + 1] = text[b * 128 + tid];
    if (tid == 0) t1s[0] = 1.f;
    __syncthreads();

    const float* zrow = Z + (size_t)b * NTOT;
    float acc = 0.f;
    for (int i = 0; i < NI; ++i)
        acc = fmaf(t1s[i], zrow[i * 128 + tid], acc);
    acc += b1[tid];
    float y1 = fmaxf(acc, 0.f);
    y1s[tid] = y1;
    __syncthreads();

    float a2 = b2[tid];
    for (int q = 0; q < 128; ++q)
        a2 = fmaf(y1s[q], W2[q * 128 + tid], a2);
    float y2 = fmaxf(a2, 0.f);

    float part = y2 * W3[tid];
#pragma unroll
    for (int off = 32; off > 0; off >>= 1)
        part += __shfl_down(part, off);
    if ((tid & 63) == 0) red[tid >> 6] = part;
    __syncthreads();
    if (tid == 0){
        float z = red[0] + red[1] + b3[0];
        out[b] = 6.f / (1.f + expf(-z)) - 3.f;
    }
}

extern "C" void kernel_launch(void* const* d_in, const int* in_sizes, int n_in,
                              void* d_out, int out_size, void* d_ws, size_t ws_size,
                              hipStream_t stream)
{
    const float* audio = (const float*)d_in[0];
    const float* video = (const float*)d_in[1];
    const float* text  = (const float*)d_in[2];
    const float* W1    = (const float*)d_in[3];
    const float* b1    = (const float*)d_in[4];
    const float* W2    = (const float*)d_in[5];
    const float* b2    = (const float*)d_in[6];
    const float* W3    = (const float*)d_in[7];
    const float* b3    = (const float*)d_in[8];
    float* out = (float*)d_out;

    char* ws = (char*)d_ws;
    uint4* af = (uint4*)ws;                       // 4,390,912 B
    float* Z  = (float*)(ws + (8u << 20));        // 33,816,576 B

    int af_granules = KBLKS * MBLKS * 64;         // 274432 threads
    build_af<<<(af_granules + 255) / 256, 256, 0, stream>>>(audio, video, af);
    fusion_gemm<<<516, 256, 0, stream>>>(W1, af, Z);
    tail_mlp<<<512, 128, 0, stream>>>(Z, text, b1, W2, b2, W3, b3, out);
}